// Round 18
// baseline (329.221 us; speedup 1.0000x reference)
//
#include <hip/hip_runtime.h>
#include <hip/hip_bf16.h>
#include <stdint.h>
#include <math.h>

#define AS1 __attribute__((address_space(1)))
#define AS3 __attribute__((address_space(3)))

typedef __bf16 bf16_t;
typedef __bf16 bf16x8 __attribute__((ext_vector_type(8)));
typedef float f32x4 __attribute__((ext_vector_type(4)));

static constexpr int B_ = 16, N_ = 616, C_ = 768, H_ = 12, HD = 64, HID = 3072;
static constexpr int NP = 640;           // padded seq len for q/k/vT
static constexpr int M_REAL = B_ * N_;   // 9856 = 154*64
static constexpr int M_PAD = 9984;       // 156*64 (packed MLP rows)
static constexpr int NT_ = 40, NI_ = 576;

__device__ __forceinline__ void gl_lds16(const void* g, void* l) {
  __builtin_amdgcn_global_load_lds((const AS1 void*)(uintptr_t)g,
                                   (AS3 void*)(uint32_t)(uintptr_t)l, 16, 0, 0);
}
__device__ __forceinline__ f32x4 mfma16(bf16x8 a, bf16x8 b, f32x4 c) {
  return __builtin_amdgcn_mfma_f32_16x16x32_bf16(a, b, c, 0, 0, 0);
}
__device__ __forceinline__ float gelu_f(float x) {
  float u = x * (0.7978845608f + 0.0356774081f * x * x);
  return x / (1.f + __expf(-2.f * u));
}

// ---------------------------------------------------------------- fused casts
struct CastArgs {
  const float* src[7];
  bf16_t* dst[7];
  int n4[7];        // quads per segment
};

__global__ __launch_bounds__(256) void cast_all(CastArgs a, int total4) {
  int i = blockIdx.x * blockDim.x + threadIdx.x;
  int st = gridDim.x * blockDim.x;
  for (; i < total4; i += st) {
    int off = i;
#pragma unroll
    for (int s = 0; s < 7; ++s) {
      if (off < a.n4[s]) {
        float4 v = ((const float4*)a.src[s])[off];
        float sub = (s == 6) ? 8.f : 0.f;
        bf16_t* d = a.dst[s] + (size_t)off * 4;
        d[0] = (bf16_t)(v.x - sub); d[1] = (bf16_t)(v.y - sub);
        d[2] = (bf16_t)(v.z - sub); d[3] = (bf16_t)(v.w - sub);
        break;
      }
      off -= a.n4[s];
    }
  }
}

// ---------------------------------------------------------------- layernorms
__global__ __launch_bounds__(256) void ln_rows(const float* __restrict__ x,
                                               const float* __restrict__ g,
                                               const float* __restrict__ b,
                                               bf16_t* __restrict__ out) {
  int r = blockIdx.x, t = threadIdx.x;
  bf16_t* orow = out + (size_t)r * C_;
  const float* xr = x + (size_t)r * C_;
  float v0 = xr[t], v1 = xr[t + 256], v2 = xr[t + 512];
  float s = v0 + v1 + v2, ss = v0 * v0 + v1 * v1 + v2 * v2;
#pragma unroll
  for (int off = 32; off > 0; off >>= 1) { s += __shfl_xor(s, off); ss += __shfl_xor(ss, off); }
  __shared__ float sm[8];
  int w = t >> 6;
  if ((t & 63) == 0) { sm[w] = s; sm[4 + w] = ss; }
  __syncthreads();
  s = sm[0] + sm[1] + sm[2] + sm[3];
  ss = sm[4] + sm[5] + sm[6] + sm[7];
  float mean = s * (1.f / C_);
  float var = ss * (1.f / C_) - mean * mean;
  float ri = rsqrtf(var + 1e-5f);
  orow[t]       = (bf16_t)((v0 - mean) * ri * g[t]       + b[t]);
  orow[t + 256] = (bf16_t)((v1 - mean) * ri * g[t + 256] + b[t + 256]);
  orow[t + 512] = (bf16_t)((v2 - mean) * ri * g[t + 512] + b[t + 512]);
}

// LN2 + pack from bf16 x1: rows [0,640)=text, [640,768)=pad, [768,9984)=image
__global__ __launch_bounds__(256) void ln2_pack(const bf16_t* __restrict__ x1,
                                                const float* __restrict__ gt, const float* __restrict__ bt,
                                                const float* __restrict__ gi, const float* __restrict__ bi,
                                                bf16_t* __restrict__ out) {
  int m = blockIdx.x, t = threadIdx.x;
  if (m >= M_REAL) {
    bf16_t* orow = out + (size_t)(640 + (m - M_REAL)) * C_;
    orow[t] = (bf16_t)0.f; orow[t+256] = (bf16_t)0.f; orow[t+512] = (bf16_t)0.f;
    return;
  }
  int b_ = m / N_, nn = m - b_ * N_;
  const float* g; const float* bb; int dest;
  if (nn < NT_) { dest = b_ * NT_ + nn; g = gt; bb = bt; }
  else          { dest = 768 + b_ * NI_ + (nn - NT_); g = gi; bb = bi; }
  const bf16_t* xr = x1 + (size_t)m * C_;
  float v0 = (float)xr[t], v1 = (float)xr[t + 256], v2 = (float)xr[t + 512];
  float s = v0 + v1 + v2, ss = v0 * v0 + v1 * v1 + v2 * v2;
#pragma unroll
  for (int off = 32; off > 0; off >>= 1) { s += __shfl_xor(s, off); ss += __shfl_xor(ss, off); }
  __shared__ float sm[8];
  int w = t >> 6;
  if ((t & 63) == 0) { sm[w] = s; sm[4 + w] = ss; }
  __syncthreads();
  s = sm[0] + sm[1] + sm[2] + sm[3];
  ss = sm[4] + sm[5] + sm[6] + sm[7];
  float mean = s * (1.f / C_);
  float var = ss * (1.f / C_) - mean * mean;
  float ri = rsqrtf(var + 1e-5f);
  bf16_t* orow = out + (size_t)dest * C_;
  orow[t]       = (bf16_t)((v0 - mean) * ri * g[t]       + bb[t]);
  orow[t + 256] = (bf16_t)((v1 - mean) * ri * g[t + 256] + bb[t + 256]);
  orow[t + 512] = (bf16_t)((v2 - mean) * ri * g[t + 512] + bb[t + 512]);
}

// ---------------------------------------------------------------- v transpose
__global__ __launch_bounds__(256) void transpose_v(const bf16_t* __restrict__ v,
                                                   bf16_t* __restrict__ vT) {
  __shared__ bf16_t t[64][80];
  int n0 = blockIdx.x * 64, bh = blockIdx.y;
  int tid = threadIdx.x;
  int r0 = tid >> 2, c0 = (tid & 3) * 16;
  int n = n0 + r0;
#pragma unroll
  for (int cc = 0; cc < 2; ++cc) {
    bf16x8 vv;
    if (n < N_) vv = *(const bf16x8*)(v + ((size_t)bh * N_ + n) * HD + c0 + cc * 8);
    else {
#pragma unroll
      for (int e = 0; e < 8; ++e) vv[e] = (bf16_t)0.f;
    }
#pragma unroll
    for (int e = 0; e < 8; ++e) t[c0 + cc * 8 + e][r0] = vv[e];
  }
  __syncthreads();
  int d = tid >> 2, nc = (tid & 3) * 16;
  bf16_t* dst = vT + ((size_t)(bh * HD + d)) * NP + n0 + nc;
  *(bf16x8*)dst       = *(const bf16x8*)&t[d][nc];
  *(bf16x8*)(dst + 8) = *(const bf16x8*)&t[d][nc + 8];
}

// ---------------------------------------------------------------- shared epilogue params
struct EpiP {
  const float* bias;
  const float* bias_i;
  const float* bias2;
  const float* gamma;
  const float* xres;     // f32 residual (proj)
  const bf16_t* xresb;   // bf16 residual (mlp2)
  float* outf;           // f32 out (mlp2 -> d_out)
  bf16_t* outfb;         // bf16 out (proj -> x1)
  bf16_t* ob0;
  bf16_t* ob1;
  bf16_t* ob2;
};

// ---------------------------------------------------------------- GEMM 64x128, counted-vmcnt dbuf pipeline (r18)
// r14 geometry (BM=64, BN=128, 4 waves, acc 4x2) + T4 schedule:
//   prologue STAGE(0,0), STAGE(1,1).
//   iter t: vmcnt(6) [tile t landed; t+1's 6 loads stay in flight]
//           -> s_barrier -> sched_barrier -> ds_read + 16 MFMA
//           -> lgkmcnt(0) -> s_barrier -> STAGE(buf t&1, t+2).
//   NEVER vmcnt(0) mid-loop: no DMA drain (r16's __syncthreads drained it).
// LDS 48 KB dbuf -> 3 blocks/CU (bounds 256,3).
template <int EPI>
__global__ __launch_bounds__(256, 3) void gemm64p(const bf16_t* __restrict__ A,
                                                  const bf16_t* __restrict__ Bt,
                                                  const bf16_t* __restrict__ Bi,
                                                  int K, int MBc, int nb, int tb, EpiP P) {
  __shared__ bf16_t As[2][4096], Bs[2][8192];   // 16 KB + 32 KB
  const int tid = threadIdx.x, lane = tid & 63, w = tid >> 6;
  const int l16 = lane & 15, lq = lane >> 4;
  const int NTk = K >> 6;

  int mblk, nblk;
  {
    int nwg = MBc * nb;
    int bid = blockIdx.x;
    int q8 = nwg >> 3, r8 = nwg & 7;
    int xcd = bid & 7, sidx = bid >> 3;
    int wg = (xcd < r8 ? xcd * (q8 + 1) : r8 * (q8 + 1) + (xcd - r8) * q8) + sidx;
    mblk = wg / nb; nblk = wg - mblk * nb;   // n-fast: A-panel L2 reuse
  }
  const int m0 = mblk * 64, n0 = nblk * 128;
  const bf16_t* Bw = (mblk < tb) ? Bt : Bi;

  f32x4 acc[4][2] = {};

  const int swsrc = ((lane & 7) ^ ((lane >> 3) & 7)) * 8;
  size_t aoff[2]; int aldso[2];
  size_t boff[4]; int bldso[4];
#pragma unroll
  for (int j = 0; j < 2; ++j) {
    int srow = w * 16 + j * 8 + (lane >> 3);          // A rows 0..63
    aoff[j] = (size_t)(m0 + srow) * K + swsrc;
    aldso[j] = (w * 128 + j * 64) * 8;
  }
#pragma unroll
  for (int j = 0; j < 4; ++j) {
    int srow = w * 32 + j * 8 + (lane >> 3);          // B rows (out cols) 0..127
    boff[j] = (size_t)(n0 + srow) * K + swsrc;
    bldso[j] = (w * 256 + j * 64) * 8;
  }
  const int sw0 = ((0 * 4 + lq) ^ (l16 & 7)) * 8;
  const int sw1 = ((1 * 4 + lq) ^ (l16 & 7)) * 8;
  const int rbA = l16 * 64;                 // all waves share all 64 A-rows
  const int rbB = (w * 32 + l16) * 64;      // wave col strip

  auto STAGE = [&](int c, int t) {
    const size_t kadd = (size_t)t * 64;
#pragma unroll
    for (int j = 0; j < 2; ++j) gl_lds16(A + aoff[j] + kadd, &As[c][0] + aldso[j]);
#pragma unroll
    for (int j = 0; j < 4; ++j) gl_lds16(Bw + boff[j] + kadd, &Bs[c][0] + bldso[j]);
  };

  STAGE(0, 0);
  if (NTk > 1) STAGE(1, 1);

  for (int t = 0; t < NTk; ++t) {
    const int c = t & 1;
    // tile t landed (6 = tile t+1's loads remain in flight); in-order retirement
    if (t + 1 < NTk) asm volatile("s_waitcnt vmcnt(6)" ::: "memory");
    else             asm volatile("s_waitcnt vmcnt(0)" ::: "memory");
    __builtin_amdgcn_s_barrier();            // all waves' tile-t loads landed
    __builtin_amdgcn_sched_barrier(0);       // fence: no ds_read hoist above

    const bf16_t* Ac = &As[c][0];
    const bf16_t* Bc = &Bs[c][0];
    bf16x8 av[4][2], bv[2][2];
#pragma unroll
    for (int i = 0; i < 4; ++i) {
      av[i][0] = *(const bf16x8*)(Ac + rbA + i * 1024 + sw0);
      av[i][1] = *(const bf16x8*)(Ac + rbA + i * 1024 + sw1);
    }
#pragma unroll
    for (int j = 0; j < 2; ++j) {
      bv[j][0] = *(const bf16x8*)(Bc + rbB + j * 1024 + sw0);
      bv[j][1] = *(const bf16x8*)(Bc + rbB + j * 1024 + sw1);
    }
#pragma unroll
    for (int kk = 0; kk < 2; ++kk)
#pragma unroll
      for (int i = 0; i < 4; ++i)
#pragma unroll
        for (int j = 0; j < 2; ++j)
          acc[i][j] = mfma16(av[i][kk], bv[j][kk], acc[i][j]);

    asm volatile("s_waitcnt lgkmcnt(0)" ::: "memory");  // my reads of buf c done
    __builtin_amdgcn_sched_barrier(0);       // fence: no ds_read sinks below
    __builtin_amdgcn_s_barrier();            // ALL waves done reading buf c
    if (t + 2 < NTk) STAGE(c, t + 2);        // safe overwrite; lands in ~1 iter
  }

  const float* bsel = (mblk < tb) ? P.bias : P.bias_i;
  (void)bsel;
  int which = n0 / C_;
#pragma unroll
  for (int i = 0; i < 4; ++i) {
    int mb = m0 + i * 16 + lq * 4;
#pragma unroll
    for (int j = 0; j < 2; ++j) {
      int jc = n0 + w * 32 + j * 16 + l16;
#pragma unroll
      for (int rr = 0; rr < 4; ++rr) {
        int m = mb + rr;
        float v = acc[i][j][rr];
        if constexpr (EPI == 0) {         // QKV split (MBc=154: m < 9856 always)
          int b_ = m / N_, nn = m - b_ * N_;
          int jj = jc - which * C_;
          int hh = jj >> 6, d = jj & 63;
          int bh = b_ * H_ + hh;
          if (which == 0) {
            P.ob0[((size_t)bh * NP + nn) * HD + d] = (bf16_t)((v + P.bias[jj]) * 0.125f);
          } else if (which == 1) {
            P.ob1[((size_t)bh * NP + nn) * HD + d] = (bf16_t)v;
          } else {
            P.ob2[((size_t)bh * N_ + nn) * HD + d] = (bf16_t)(v + P.bias2[jj]);
          }
        } else if constexpr (EPI == 1) {  // proj: x1(bf16) = x + gamma1*(o+b)
          size_t idx = (size_t)m * C_ + jc;
          P.outfb[idx] = (bf16_t)(P.xres[idx] + P.gamma[jc] * (v + P.bias[jc]));
        } else if constexpr (EPI == 2) {  // mlp1: gelu -> hbuf (pad rows finite)
          P.ob0[(size_t)m * HID + jc] = (bf16_t)gelu_f(v + bsel[jc]);
        } else {                          // mlp2: out(f32) = x1(bf16) + gamma2*(h+b)
          int orig = -1;
          if (m < 640)      orig = (m / NT_) * N_ + (m - (m / NT_) * NT_);
          else if (m >= 768) {
            int mi = m - 768;
            int bb = mi / NI_;
            orig = bb * N_ + NT_ + (mi - bb * NI_);
          }
          if (orig >= 0) {
            size_t idx = (size_t)orig * C_ + jc;
            P.outf[idx] = (float)P.xresb[idx] + P.gamma[jc] * (v + bsel[jc]);
          }
        }
      }
    }
  }
}

// ---------------------------------------------------------------- attention (validated r10)
__global__ __launch_bounds__(256) void attn_fwd(const bf16_t* __restrict__ qb,
                                                const bf16_t* __restrict__ kb,
                                                const bf16_t* __restrict__ vT,
                                                const bf16_t* __restrict__ biasb,
                                                bf16_t* __restrict__ o_mat) {
  __shared__ bf16_t qs[64 * 64];
  __shared__ bf16_t ks[2][64 * 64], vs[2][64 * 64];
  __shared__ bf16_t ps[4][16 * 72];
  const int tid = threadIdx.x, lane = tid & 63, w = tid >> 6;
  const int l16 = lane & 15, lq = lane >> 4;
  int wg = (blockIdx.x & 7) * 240 + (blockIdx.x >> 3);
  const int qt = wg % 10;
  const int rb = wg / 10;
  const int b_ = rb & 15, h = rb >> 4;
  const int bh = b_ * H_ + h;
  const int q0 = qt * 64;
  const int swr = (l16 & 7);
  constexpr int NKT = NP / 64;

  const bf16_t* ksrc = kb + (size_t)bh * NP * HD;
  const bf16_t* vsrc = vT + (size_t)bh * HD * NP;

  auto stage_kv = [&](int c, int kt) {
    int n0k = kt * 64;
#pragma unroll
    for (int it = 0; it < 2; ++it) {
      int cb = it * 256 + w * 64, cc = cb + lane;
      int row = cc >> 3, sg = (cc & 7) ^ ((cc >> 3) & 7);
      gl_lds16(ksrc + ((size_t)(n0k + row)) * HD + sg * 8, ks[c] + cb * 8);
      gl_lds16(vsrc + (size_t)row * NP + n0k + sg * 8, vs[c] + cb * 8);
    }
  };

  const bf16_t* qsrc = qb + ((size_t)bh * NP + q0) * HD;
#pragma unroll
  for (int it = 0; it < 2; ++it) {
    int cb = it * 256 + w * 64, c = cb + lane;
    int row = c >> 3, sg = (c & 7) ^ ((c >> 3) & 7);
    gl_lds16(qsrc + row * 64 + sg * 8, qs + cb * 8);
  }
  stage_kv(0, 0);
  __syncthreads();

  bf16x8 aq[2];
  aq[0] = *(const bf16x8*)(qs + (w * 16 + l16) * 64 + ((0 * 4 + lq) ^ swr) * 8);
  aq[1] = *(const bf16x8*)(qs + (w * 16 + l16) * 64 + ((1 * 4 + lq) ^ swr) * 8);

  float lsum[4] = {0.f, 0.f, 0.f, 0.f};
  f32x4 oacc[4] = {};
  const int qrow_base = q0 + w * 16 + lq * 4;

  const bf16_t* bp[4];
#pragma unroll
  for (int r = 0; r < 4; ++r) {
    int qg = qrow_base + r;
    int qc = qg < N_ ? qg : (N_ - 1);
    bp[r] = biasb + (size_t)h * N_ * N_ + (size_t)qc * N_;
  }

  for (int kt = 0; kt < NKT; ++kt) {
    const int c = kt & 1;
    if (kt > 0) __syncthreads();
    if (kt + 1 < NKT) stage_kv(c ^ 1, kt + 1);

    f32x4 sf[4];
#pragma unroll
    for (int f = 0; f < 4; ++f) {
      f32x4 z = {};
#pragma unroll
      for (int kk = 0; kk < 2; ++kk) {
        bf16x8 bk = *(const bf16x8*)(ks[c] + (f * 16 + l16) * 64 + ((kk * 4 + lq) ^ swr) * 8);
        z = mfma16(aq[kk], bk, z);
      }
      sf[f] = z;
    }

    int n0k = kt * 64;
    bf16_t* psw = ps[w];
    if (kt < NKT - 1) {
#pragma unroll
      for (int f = 0; f < 4; ++f) {
        int kc = n0k + f * 16 + l16;
#pragma unroll
        for (int r = 0; r < 4; ++r) {
          float p = __expf(sf[f][r] + (float)bp[r][kc]);
          lsum[r] += p;
          psw[(lq * 4 + r) * 72 + f * 16 + l16] = (bf16_t)p;
        }
      }
    } else {
#pragma unroll
      for (int f = 0; f < 4; ++f) {
        int kc = n0k + f * 16 + l16;
        bool ok = kc < N_;
        int kcs = ok ? kc : 0;
#pragma unroll
        for (int r = 0; r < 4; ++r) {
          float p = ok ? __expf(sf[f][r] + (float)bp[r][kcs]) : 0.f;
          lsum[r] += p;
          psw[(lq * 4 + r) * 72 + f * 16 + l16] = (bf16_t)p;
        }
      }
    }

#pragma unroll
    for (int kk = 0; kk < 2; ++kk) {
      bf16x8 pa = *(const bf16x8*)(psw + l16 * 72 + kk * 32 + lq * 8);
#pragma unroll
      for (int df = 0; df < 4; ++df) {
        bf16x8 bv = *(const bf16x8*)(vs[c] + (df * 16 + l16) * 64 + ((kk * 4 + lq) ^ swr) * 8);
        oacc[df] = mfma16(pa, bv, oacc[df]);
      }
    }
  }

#pragma unroll
  for (int off = 1; off < 16; off <<= 1)
#pragma unroll
    for (int r = 0; r < 4; ++r)
      lsum[r] += __shfl_xor(lsum[r], off, 16);

#pragma unroll
  for (int r = 0; r < 4; ++r) {
    int qg = qrow_base + r;
    if (qg < N_) {
      float rl = 1.f / lsum[r];
      size_t orow = ((size_t)(b_ * N_ + qg)) * C_ + h * HD;
#pragma unroll
      for (int df = 0; df < 4; ++df)
        o_mat[orow + df * 16 + l16] = (bf16_t)(oacc[df][r] * rl);
    }
  }
}

// ---------------------------------------------------------------- launch
extern "C" void kernel_launch(void* const* d_in, const int* in_sizes, int n_in,
                              void* d_out, int out_size, void* d_ws, size_t ws_size,
                              hipStream_t stream) {
  const float* x      = (const float*)d_in[0];
  const float* rel    = (const float*)d_in[1];
  const float* ln1_g  = (const float*)d_in[2];
  const float* ln1_b  = (const float*)d_in[3];
  const float* w_qkv  = (const float*)d_in[4];
  const float* q_bias = (const float*)d_in[5];
  const float* v_bias = (const float*)d_in[6];
  const float* w_proj = (const float*)d_in[7];
  const float* b_proj = (const float*)d_in[8];
  const float* gamma1 = (const float*)d_in[9];
  const float* gamma2 = (const float*)d_in[10];
  const float* ln2t_g = (const float*)d_in[11];
  const float* ln2t_b = (const float*)d_in[12];
  const float* ln2i_g = (const float*)d_in[13];
  const float* ln2i_b = (const float*)d_in[14];
  const float* wt1    = (const float*)d_in[15];
  const float* bt1    = (const float*)d_in[16];
  const float* wt2    = (const float*)d_in[17];
  const float* bt2    = (const float*)d_in[18];
  const float* wi1    = (const float*)d_in[19];
  const float* bi1    = (const float*)d_in[20];
  const float* wi2    = (const float*)d_in[21];
  const float* bi2    = (const float*)d_in[22];
  float* out = (float*)d_out;

  char* ws = (char*)d_ws;
  bf16_t* wqkvb  = (bf16_t*)(ws + 0);
  bf16_t* wprojb = (bf16_t*)(ws + 3538944);
  bf16_t* wt1b   = (bf16_t*)(ws + 4718592);
  bf16_t* wi1b   = (bf16_t*)(ws + 9437184);
  bf16_t* wt2b   = (bf16_t*)(ws + 14155776);
  bf16_t* wi2b   = (bf16_t*)(ws + 18874368);
  bf16_t* n1     = (bf16_t*)(ws + 23592960);    // 9984x768 bf16; also n2p, o_mat
  bf16_t* x1b    = (bf16_t*)(ws + 38928384);    // 15.1MB bf16 x1; head doubles as vtmp
  bf16_t* qbuf   = (bf16_t*)(ws + 69206016);
  bf16_t* kbuf   = (bf16_t*)(ws + 84934656);
  bf16_t* vTbuf  = (bf16_t*)(ws + 100663296);
  bf16_t* biasb  = (bf16_t*)(ws + 116391936);   // 9.1 MB
  bf16_t* vtmp   = (bf16_t*)(ws + 38928384);    // dead before x1b written
  bf16_t* o_mat  = n1;
  bf16_t* n2p    = n1;
  bf16_t* hbuf   = qbuf;

  // one fused cast launch (weights + shifted bias)
  {
    CastArgs a;
    a.src[0] = w_qkv;  a.dst[0] = wqkvb;  a.n4[0] = (3 * C_ * C_) / 4;
    a.src[1] = w_proj; a.dst[1] = wprojb; a.n4[1] = (C_ * C_) / 4;
    a.src[2] = wt1;    a.dst[2] = wt1b;   a.n4[2] = (HID * C_) / 4;
    a.src[3] = wi1;    a.dst[3] = wi1b;   a.n4[3] = (HID * C_) / 4;
    a.src[4] = wt2;    a.dst[4] = wt2b;   a.n4[4] = (C_ * HID) / 4;
    a.src[5] = wi2;    a.dst[5] = wi2b;   a.n4[5] = (C_ * HID) / 4;
    a.src[6] = rel;    a.dst[6] = biasb;  a.n4[6] = (H_ * N_ * N_) / 4;
    int total4 = a.n4[0] + a.n4[1] + a.n4[2] + a.n4[3] + a.n4[4] + a.n4[5] + a.n4[6];
    cast_all<<<2048, 256, 0, stream>>>(a, total4);
  }
  ln_rows<<<M_REAL, 256, 0, stream>>>(x, ln1_g, ln1_b, n1);

  // QKV GEMM: 154 x 18 blocks
  {
    EpiP P{}; P.bias = q_bias; P.bias2 = v_bias;
    P.ob0 = qbuf; P.ob1 = kbuf; P.ob2 = vtmp;
    gemm64p<0><<<154 * 18, 256, 0, stream>>>(n1, wqkvb, wqkvb, C_, 154, 18, 0, P);
  }
  transpose_v<<<dim3(NP / 64, B_ * H_), 256, 0, stream>>>(vtmp, vTbuf);
  attn_fwd<<<1920, 256, 0, stream>>>(qbuf, kbuf, vTbuf, biasb, o_mat);

  // proj + residual -> x1 (bf16): 154 x 6 blocks
  {
    EpiP P{}; P.bias = b_proj; P.bias_i = b_proj; P.gamma = gamma1; P.xres = x; P.outfb = x1b;
    gemm64p<1><<<154 * 6, 256, 0, stream>>>(o_mat, wprojb, wprojb, C_, 154, 6, 0, P);
  }
  ln2_pack<<<M_PAD, 256, 0, stream>>>(x1b, ln2t_g, ln2t_b, ln2i_g, ln2i_b, n2p);

  // MLP fc1 + gelu: 156 x 24 blocks (text/pad m-blocks 0-11 -> tb=12)
  {
    EpiP P{}; P.bias = bt1; P.bias_i = bi1; P.ob0 = hbuf;
    gemm64p<2><<<156 * 24, 256, 0, stream>>>(n2p, wt1b, wi1b, C_, 156, 24, 12, P);
  }
  // MLP fc2 + gamma2 residual -> d_out: 156 x 6 blocks (tb=12)
  {
    EpiP P{}; P.bias = bt2; P.bias_i = bi2; P.gamma = gamma2; P.xresb = x1b; P.outf = out;
    gemm64p<3><<<156 * 6, 256, 0, stream>>>(hbuf, wt2b, wi2b, HID, 156, 6, 12, P);
  }
}

// Round 19
// 295.615 us; speedup vs baseline: 1.1137x; 1.1137x over previous
//
#include <hip/hip_runtime.h>
#include <hip/hip_bf16.h>
#include <stdint.h>
#include <math.h>

#define AS1 __attribute__((address_space(1)))
#define AS3 __attribute__((address_space(3)))

typedef __bf16 bf16_t;
typedef __bf16 bf16x8 __attribute__((ext_vector_type(8)));
typedef float f32x4 __attribute__((ext_vector_type(4)));

static constexpr int B_ = 16, N_ = 616, C_ = 768, H_ = 12, HD = 64, HID = 3072;
static constexpr int NP = 640;           // padded seq len for q/k/vT
static constexpr int M_REAL = B_ * N_;   // 9856 = 77*128 = 154*64
static constexpr int M_PAD = 9984;       // 78*128 = 156*64 (packed MLP rows)
static constexpr int NT_ = 40, NI_ = 576;

__device__ __forceinline__ void gl_lds16(const void* g, void* l) {
  __builtin_amdgcn_global_load_lds((const AS1 void*)(uintptr_t)g,
                                   (AS3 void*)(uint32_t)(uintptr_t)l, 16, 0, 0);
}
__device__ __forceinline__ f32x4 mfma16(bf16x8 a, bf16x8 b, f32x4 c) {
  return __builtin_amdgcn_mfma_f32_16x16x32_bf16(a, b, c, 0, 0, 0);
}
__device__ __forceinline__ float gelu_f(float x) {
  float u = x * (0.7978845608f + 0.0356774081f * x * x);
  return x / (1.f + __expf(-2.f * u));
}

// ---------------------------------------------------------------- fused casts
struct CastArgs {
  const float* src[7];
  bf16_t* dst[7];
  int n4[7];        // quads per segment
};

__global__ __launch_bounds__(256) void cast_all(CastArgs a, int total4) {
  int i = blockIdx.x * blockDim.x + threadIdx.x;
  int st = gridDim.x * blockDim.x;
  for (; i < total4; i += st) {
    int off = i;
#pragma unroll
    for (int s = 0; s < 7; ++s) {
      if (off < a.n4[s]) {
        float4 v = ((const float4*)a.src[s])[off];
        float sub = (s == 6) ? 8.f : 0.f;
        bf16_t* d = a.dst[s] + (size_t)off * 4;
        d[0] = (bf16_t)(v.x - sub); d[1] = (bf16_t)(v.y - sub);
        d[2] = (bf16_t)(v.z - sub); d[3] = (bf16_t)(v.w - sub);
        break;
      }
      off -= a.n4[s];
    }
  }
}

// ---------------------------------------------------------------- layernorms
__global__ __launch_bounds__(256) void ln_rows(const float* __restrict__ x,
                                               const float* __restrict__ g,
                                               const float* __restrict__ b,
                                               bf16_t* __restrict__ out) {
  int r = blockIdx.x, t = threadIdx.x;
  bf16_t* orow = out + (size_t)r * C_;
  const float* xr = x + (size_t)r * C_;
  float v0 = xr[t], v1 = xr[t + 256], v2 = xr[t + 512];
  float s = v0 + v1 + v2, ss = v0 * v0 + v1 * v1 + v2 * v2;
#pragma unroll
  for (int off = 32; off > 0; off >>= 1) { s += __shfl_xor(s, off); ss += __shfl_xor(ss, off); }
  __shared__ float sm[8];
  int w = t >> 6;
  if ((t & 63) == 0) { sm[w] = s; sm[4 + w] = ss; }
  __syncthreads();
  s = sm[0] + sm[1] + sm[2] + sm[3];
  ss = sm[4] + sm[5] + sm[6] + sm[7];
  float mean = s * (1.f / C_);
  float var = ss * (1.f / C_) - mean * mean;
  float ri = rsqrtf(var + 1e-5f);
  orow[t]       = (bf16_t)((v0 - mean) * ri * g[t]       + b[t]);
  orow[t + 256] = (bf16_t)((v1 - mean) * ri * g[t + 256] + b[t + 256]);
  orow[t + 512] = (bf16_t)((v2 - mean) * ri * g[t + 512] + b[t + 512]);
}

// LN2 + pack from bf16 x1: rows [0,640)=text, [640,768)=pad, [768,9984)=image
__global__ __launch_bounds__(256) void ln2_pack(const bf16_t* __restrict__ x1,
                                                const float* __restrict__ gt, const float* __restrict__ bt,
                                                const float* __restrict__ gi, const float* __restrict__ bi,
                                                bf16_t* __restrict__ out) {
  int m = blockIdx.x, t = threadIdx.x;
  if (m >= M_REAL) {
    bf16_t* orow = out + (size_t)(640 + (m - M_REAL)) * C_;
    orow[t] = (bf16_t)0.f; orow[t+256] = (bf16_t)0.f; orow[t+512] = (bf16_t)0.f;
    return;
  }
  int b_ = m / N_, nn = m - b_ * N_;
  const float* g; const float* bb; int dest;
  if (nn < NT_) { dest = b_ * NT_ + nn; g = gt; bb = bt; }
  else          { dest = 768 + b_ * NI_ + (nn - NT_); g = gi; bb = bi; }
  const bf16_t* xr = x1 + (size_t)m * C_;
  float v0 = (float)xr[t], v1 = (float)xr[t + 256], v2 = (float)xr[t + 512];
  float s = v0 + v1 + v2, ss = v0 * v0 + v1 * v1 + v2 * v2;
#pragma unroll
  for (int off = 32; off > 0; off >>= 1) { s += __shfl_xor(s, off); ss += __shfl_xor(ss, off); }
  __shared__ float sm[8];
  int w = t >> 6;
  if ((t & 63) == 0) { sm[w] = s; sm[4 + w] = ss; }
  __syncthreads();
  s = sm[0] + sm[1] + sm[2] + sm[3];
  ss = sm[4] + sm[5] + sm[6] + sm[7];
  float mean = s * (1.f / C_);
  float var = ss * (1.f / C_) - mean * mean;
  float ri = rsqrtf(var + 1e-5f);
  bf16_t* orow = out + (size_t)dest * C_;
  orow[t]       = (bf16_t)((v0 - mean) * ri * g[t]       + bb[t]);
  orow[t + 256] = (bf16_t)((v1 - mean) * ri * g[t + 256] + bb[t + 256]);
  orow[t + 512] = (bf16_t)((v2 - mean) * ri * g[t + 512] + bb[t + 512]);
}

// ---------------------------------------------------------------- v transpose
__global__ __launch_bounds__(256) void transpose_v(const bf16_t* __restrict__ v,
                                                   bf16_t* __restrict__ vT) {
  __shared__ bf16_t t[64][80];
  int n0 = blockIdx.x * 64, bh = blockIdx.y;
  int tid = threadIdx.x;
  int r0 = tid >> 2, c0 = (tid & 3) * 16;
  int n = n0 + r0;
#pragma unroll
  for (int cc = 0; cc < 2; ++cc) {
    bf16x8 vv;
    if (n < N_) vv = *(const bf16x8*)(v + ((size_t)bh * N_ + n) * HD + c0 + cc * 8);
    else {
#pragma unroll
      for (int e = 0; e < 8; ++e) vv[e] = (bf16_t)0.f;
    }
#pragma unroll
    for (int e = 0; e < 8; ++e) t[c0 + cc * 8 + e][r0] = vv[e];
  }
  __syncthreads();
  int d = tid >> 2, nc = (tid & 3) * 16;
  bf16_t* dst = vT + ((size_t)(bh * HD + d)) * NP + n0 + nc;
  *(bf16x8*)dst       = *(const bf16x8*)&t[d][nc];
  *(bf16x8*)(dst + 8) = *(const bf16x8*)&t[d][nc + 8];
}

// ---------------------------------------------------------------- shared epilogue params
struct EpiP {
  const float* bias;
  const float* bias_i;
  const float* bias2;
  const float* gamma;
  const float* xres;     // f32 residual (proj)
  const bf16_t* xresb;   // bf16 residual (mlp2)
  float* outf;           // f32 out (mlp2 -> d_out)
  bf16_t* outfb;         // bf16 out (proj -> x1)
  bf16_t* ob0;
  bf16_t* ob1;
  bf16_t* ob2;
};

// ---------------------------------------------------------------- GEMM 128x128 (r11/r12/r17 validated config)
// Single-buffer 32KB, bounds(256,3), n-fast XCD-chunked. Best measured for
// qkv/mlp1. r13's bounds-5 spilled; r16/r18 pipelines lost co-residency.
template <int EPI>
__global__ __launch_bounds__(256, 3) void gemm128(const bf16_t* __restrict__ A,
                                                  const bf16_t* __restrict__ Bt,
                                                  const bf16_t* __restrict__ Bi,
                                                  int K, int MBc, int nb, int tb, EpiP P) {
  __shared__ bf16_t As[8192], Bs[8192];
  const int tid = threadIdx.x, lane = tid & 63, w = tid >> 6;
  const int l16 = lane & 15, lq = lane >> 4;
  const int wr = w >> 1, wc = w & 1;
  const int NTk = K >> 6;

  int mblk, nblk;
  {
    int nwg = MBc * nb;
    int bid = blockIdx.x;
    int q8 = nwg >> 3, r8 = nwg & 7;
    int xcd = bid & 7, sidx = bid >> 3;
    int wg = (xcd < r8 ? xcd * (q8 + 1) : r8 * (q8 + 1) + (xcd - r8) * q8) + sidx;
    mblk = wg / nb; nblk = wg - mblk * nb;   // n-fast: A-panel L2 reuse
  }
  const int m0 = mblk * 128, n0 = nblk * 128;
  const bf16_t* Bw = (mblk < tb) ? Bt : Bi;

  f32x4 acc[4][4] = {};

  const int swsrc = ((lane & 7) ^ ((lane >> 3) & 7)) * 8;
  size_t aoff[4], boff[4];
  int ldsoff[4];
#pragma unroll
  for (int j = 0; j < 4; ++j) {
    int srow = j * 32 + w * 8 + (lane >> 3);
    aoff[j] = (size_t)(m0 + srow) * K + swsrc;
    boff[j] = (size_t)(n0 + srow) * K + swsrc;
    ldsoff[j] = (j * 256 + w * 64) * 8;
  }
  const int sw0 = ((0 * 4 + lq) ^ (l16 & 7)) * 8;
  const int sw1 = ((1 * 4 + lq) ^ (l16 & 7)) * 8;
  const int rbA = (wr * 64 + l16) * 64;
  const int rbB = (wc * 64 + l16) * 64;

  for (int t = 0; t < NTk; ++t) {
    const size_t kadd = (size_t)t * 64;
#pragma unroll
    for (int j = 0; j < 4; ++j) gl_lds16(A + aoff[j] + kadd, As + ldsoff[j]);
#pragma unroll
    for (int j = 0; j < 4; ++j) gl_lds16(Bw + boff[j] + kadd, Bs + ldsoff[j]);
    __syncthreads();

    bf16x8 av[4][2], bv[4][2];
#pragma unroll
    for (int i = 0; i < 4; ++i) {
      av[i][0] = *(const bf16x8*)(As + rbA + i * 1024 + sw0);
      av[i][1] = *(const bf16x8*)(As + rbA + i * 1024 + sw1);
      bv[i][0] = *(const bf16x8*)(Bs + rbB + i * 1024 + sw0);
      bv[i][1] = *(const bf16x8*)(Bs + rbB + i * 1024 + sw1);
    }
#pragma unroll
    for (int kk = 0; kk < 2; ++kk)
#pragma unroll
      for (int i = 0; i < 4; ++i)
#pragma unroll
        for (int j = 0; j < 4; ++j)
          acc[i][j] = mfma16(av[i][kk], bv[j][kk], acc[i][j]);
    __syncthreads();
  }

  const float* bsel = (mblk < tb) ? P.bias : P.bias_i;
  (void)bsel;
  int which = n0 / C_;
#pragma unroll
  for (int i = 0; i < 4; ++i) {
    int mb = m0 + wr * 64 + i * 16 + lq * 4;
#pragma unroll
    for (int j = 0; j < 4; ++j) {
      int jc = n0 + wc * 64 + j * 16 + l16;
#pragma unroll
      for (int rr = 0; rr < 4; ++rr) {
        int m = mb + rr;
        float v = acc[i][j][rr];
        if constexpr (EPI == 0) {         // QKV split (MBc=77: m < 9856 always)
          int b_ = m / N_, nn = m - b_ * N_;
          int jj = jc - which * C_;
          int hh = jj >> 6, d = jj & 63;
          int bh = b_ * H_ + hh;
          if (which == 0) {
            P.ob0[((size_t)bh * NP + nn) * HD + d] = (bf16_t)((v + P.bias[jj]) * 0.125f);
          } else if (which == 1) {
            P.ob1[((size_t)bh * NP + nn) * HD + d] = (bf16_t)v;
          } else {
            P.ob2[((size_t)bh * N_ + nn) * HD + d] = (bf16_t)(v + P.bias2[jj]);
          }
        } else if constexpr (EPI == 2) {  // mlp1: gelu -> hbuf (pad rows finite)
          P.ob0[(size_t)m * HID + jc] = (bf16_t)gelu_f(v + bsel[jc]);
        }
      }
    }
  }
}

// ---------------------------------------------------------------- GEMM 64x128 (r12/r17 validated config)
// Single-buffer 24KB, bounds(256,4). Best measured for proj/mlp2.
template <int EPI>
__global__ __launch_bounds__(256, 4) void gemm64(const bf16_t* __restrict__ A,
                                                 const bf16_t* __restrict__ Bt,
                                                 const bf16_t* __restrict__ Bi,
                                                 int K, int MBc, int nb, int tb, EpiP P) {
  __shared__ bf16_t As[4096], Bs[8192];
  const int tid = threadIdx.x, lane = tid & 63, w = tid >> 6;
  const int l16 = lane & 15, lq = lane >> 4;
  const int NTk = K >> 6;

  int mblk, nblk;
  {
    int nwg = MBc * nb;
    int bid = blockIdx.x;
    int q8 = nwg >> 3, r8 = nwg & 7;
    int xcd = bid & 7, sidx = bid >> 3;
    int wg = (xcd < r8 ? xcd * (q8 + 1) : r8 * (q8 + 1) + (xcd - r8) * q8) + sidx;
    mblk = wg / nb; nblk = wg - mblk * nb;   // n-fast
  }
  const int m0 = mblk * 64, n0 = nblk * 128;
  const bf16_t* Bw = (mblk < tb) ? Bt : Bi;

  f32x4 acc[4][2] = {};

  const int swsrc = ((lane & 7) ^ ((lane >> 3) & 7)) * 8;
  size_t aoff[2]; int aldso[2];
  size_t boff[4]; int bldso[4];
#pragma unroll
  for (int j = 0; j < 2; ++j) {
    int srow = w * 16 + j * 8 + (lane >> 3);
    aoff[j] = (size_t)(m0 + srow) * K + swsrc;
    aldso[j] = (w * 128 + j * 64) * 8;
  }
#pragma unroll
  for (int j = 0; j < 4; ++j) {
    int srow = w * 32 + j * 8 + (lane >> 3);
    boff[j] = (size_t)(n0 + srow) * K + swsrc;
    bldso[j] = (w * 256 + j * 64) * 8;
  }
  const int sw0 = ((0 * 4 + lq) ^ (l16 & 7)) * 8;
  const int sw1 = ((1 * 4 + lq) ^ (l16 & 7)) * 8;
  const int rbA = l16 * 64;
  const int rbB = (w * 32 + l16) * 64;

  for (int t = 0; t < NTk; ++t) {
    const size_t kadd = (size_t)t * 64;
#pragma unroll
    for (int j = 0; j < 2; ++j) gl_lds16(A + aoff[j] + kadd, As + aldso[j]);
#pragma unroll
    for (int j = 0; j < 4; ++j) gl_lds16(Bw + boff[j] + kadd, Bs + bldso[j]);
    __syncthreads();

    bf16x8 av[4][2], bv[2][2];
#pragma unroll
    for (int i = 0; i < 4; ++i) {
      av[i][0] = *(const bf16x8*)(As + rbA + i * 1024 + sw0);
      av[i][1] = *(const bf16x8*)(As + rbA + i * 1024 + sw1);
    }
#pragma unroll
    for (int j = 0; j < 2; ++j) {
      bv[j][0] = *(const bf16x8*)(Bs + rbB + j * 1024 + sw0);
      bv[j][1] = *(const bf16x8*)(Bs + rbB + j * 1024 + sw1);
    }
#pragma unroll
    for (int kk = 0; kk < 2; ++kk)
#pragma unroll
      for (int i = 0; i < 4; ++i)
#pragma unroll
        for (int j = 0; j < 2; ++j)
          acc[i][j] = mfma16(av[i][kk], bv[j][kk], acc[i][j]);
    __syncthreads();
  }

  const float* bsel = (mblk < tb) ? P.bias : P.bias_i;
  (void)bsel;
#pragma unroll
  for (int i = 0; i < 4; ++i) {
    int mb = m0 + i * 16 + lq * 4;
#pragma unroll
    for (int j = 0; j < 2; ++j) {
      int jc = n0 + w * 32 + j * 16 + l16;
#pragma unroll
      for (int rr = 0; rr < 4; ++rr) {
        int m = mb + rr;
        float v = acc[i][j][rr];
        if constexpr (EPI == 1) {         // proj: x1(bf16) = x + gamma1*(o+b)
          size_t idx = (size_t)m * C_ + jc;
          P.outfb[idx] = (bf16_t)(P.xres[idx] + P.gamma[jc] * (v + P.bias[jc]));
        } else {                          // mlp2: out(f32) = x1(bf16) + gamma2*(h+b)
          int orig = -1;
          if (m < 640)      orig = (m / NT_) * N_ + (m - (m / NT_) * NT_);
          else if (m >= 768) {
            int mi = m - 768;
            int bb = mi / NI_;
            orig = bb * N_ + NT_ + (mi - bb * NI_);
          }
          if (orig >= 0) {
            size_t idx = (size_t)orig * C_ + jc;
            P.outf[idx] = (float)P.xresb[idx] + P.gamma[jc] * (v + bsel[jc]);
          }
        }
      }
    }
  }
}

// ---------------------------------------------------------------- attention (validated r10)
__global__ __launch_bounds__(256) void attn_fwd(const bf16_t* __restrict__ qb,
                                                const bf16_t* __restrict__ kb,
                                                const bf16_t* __restrict__ vT,
                                                const bf16_t* __restrict__ biasb,
                                                bf16_t* __restrict__ o_mat) {
  __shared__ bf16_t qs[64 * 64];
  __shared__ bf16_t ks[2][64 * 64], vs[2][64 * 64];
  __shared__ bf16_t ps[4][16 * 72];
  const int tid = threadIdx.x, lane = tid & 63, w = tid >> 6;
  const int l16 = lane & 15, lq = lane >> 4;
  int wg = (blockIdx.x & 7) * 240 + (blockIdx.x >> 3);
  const int qt = wg % 10;
  const int rb = wg / 10;
  const int b_ = rb & 15, h = rb >> 4;
  const int bh = b_ * H_ + h;
  const int q0 = qt * 64;
  const int swr = (l16 & 7);
  constexpr int NKT = NP / 64;

  const bf16_t* ksrc = kb + (size_t)bh * NP * HD;
  const bf16_t* vsrc = vT + (size_t)bh * HD * NP;

  auto stage_kv = [&](int c, int kt) {
    int n0k = kt * 64;
#pragma unroll
    for (int it = 0; it < 2; ++it) {
      int cb = it * 256 + w * 64, cc = cb + lane;
      int row = cc >> 3, sg = (cc & 7) ^ ((cc >> 3) & 7);
      gl_lds16(ksrc + ((size_t)(n0k + row)) * HD + sg * 8, ks[c] + cb * 8);
      gl_lds16(vsrc + (size_t)row * NP + n0k + sg * 8, vs[c] + cb * 8);
    }
  };

  const bf16_t* qsrc = qb + ((size_t)bh * NP + q0) * HD;
#pragma unroll
  for (int it = 0; it < 2; ++it) {
    int cb = it * 256 + w * 64, c = cb + lane;
    int row = c >> 3, sg = (c & 7) ^ ((c >> 3) & 7);
    gl_lds16(qsrc + row * 64 + sg * 8, qs + cb * 8);
  }
  stage_kv(0, 0);
  __syncthreads();

  bf16x8 aq[2];
  aq[0] = *(const bf16x8*)(qs + (w * 16 + l16) * 64 + ((0 * 4 + lq) ^ swr) * 8);
  aq[1] = *(const bf16x8*)(qs + (w * 16 + l16) * 64 + ((1 * 4 + lq) ^ swr) * 8);

  float lsum[4] = {0.f, 0.f, 0.f, 0.f};
  f32x4 oacc[4] = {};
  const int qrow_base = q0 + w * 16 + lq * 4;

  const bf16_t* bp[4];
#pragma unroll
  for (int r = 0; r < 4; ++r) {
    int qg = qrow_base + r;
    int qc = qg < N_ ? qg : (N_ - 1);
    bp[r] = biasb + (size_t)h * N_ * N_ + (size_t)qc * N_;
  }

  for (int kt = 0; kt < NKT; ++kt) {
    const int c = kt & 1;
    if (kt > 0) __syncthreads();
    if (kt + 1 < NKT) stage_kv(c ^ 1, kt + 1);

    f32x4 sf[4];
#pragma unroll
    for (int f = 0; f < 4; ++f) {
      f32x4 z = {};
#pragma unroll
      for (int kk = 0; kk < 2; ++kk) {
        bf16x8 bk = *(const bf16x8*)(ks[c] + (f * 16 + l16) * 64 + ((kk * 4 + lq) ^ swr) * 8);
        z = mfma16(aq[kk], bk, z);
      }
      sf[f] = z;
    }

    int n0k = kt * 64;
    bf16_t* psw = ps[w];
    if (kt < NKT - 1) {
#pragma unroll
      for (int f = 0; f < 4; ++f) {
        int kc = n0k + f * 16 + l16;
#pragma unroll
        for (int r = 0; r < 4; ++r) {
          float p = __expf(sf[f][r] + (float)bp[r][kc]);
          lsum[r] += p;
          psw[(lq * 4 + r) * 72 + f * 16 + l16] = (bf16_t)p;
        }
      }
    } else {
#pragma unroll
      for (int f = 0; f < 4; ++f) {
        int kc = n0k + f * 16 + l16;
        bool ok = kc < N_;
        int kcs = ok ? kc : 0;
#pragma unroll
        for (int r = 0; r < 4; ++r) {
          float p = ok ? __expf(sf[f][r] + (float)bp[r][kcs]) : 0.f;
          lsum[r] += p;
          psw[(lq * 4 + r) * 72 + f * 16 + l16] = (bf16_t)p;
        }
      }
    }

#pragma unroll
    for (int kk = 0; kk < 2; ++kk) {
      bf16x8 pa = *(const bf16x8*)(psw + l16 * 72 + kk * 32 + lq * 8);
#pragma unroll
      for (int df = 0; df < 4; ++df) {
        bf16x8 bv = *(const bf16x8*)(vs[c] + (df * 16 + l16) * 64 + ((kk * 4 + lq) ^ swr) * 8);
        oacc[df] = mfma16(pa, bv, oacc[df]);
      }
    }
  }

#pragma unroll
  for (int off = 1; off < 16; off <<= 1)
#pragma unroll
    for (int r = 0; r < 4; ++r)
      lsum[r] += __shfl_xor(lsum[r], off, 16);

#pragma unroll
  for (int r = 0; r < 4; ++r) {
    int qg = qrow_base + r;
    if (qg < N_) {
      float rl = 1.f / lsum[r];
      size_t orow = ((size_t)(b_ * N_ + qg)) * C_ + h * HD;
#pragma unroll
      for (int df = 0; df < 4; ++df)
        o_mat[orow + df * 16 + l16] = (bf16_t)(oacc[df][r] * rl);
    }
  }
}

// ---------------------------------------------------------------- launch
extern "C" void kernel_launch(void* const* d_in, const int* in_sizes, int n_in,
                              void* d_out, int out_size, void* d_ws, size_t ws_size,
                              hipStream_t stream) {
  const float* x      = (const float*)d_in[0];
  const float* rel    = (const float*)d_in[1];
  const float* ln1_g  = (const float*)d_in[2];
  const float* ln1_b  = (const float*)d_in[3];
  const float* w_qkv  = (const float*)d_in[4];
  const float* q_bias = (const float*)d_in[5];
  const float* v_bias = (const float*)d_in[6];
  const float* w_proj = (const float*)d_in[7];
  const float* b_proj = (const float*)d_in[8];
  const float* gamma1 = (const float*)d_in[9];
  const float* gamma2 = (const float*)d_in[10];
  const float* ln2t_g = (const float*)d_in[11];
  const float* ln2t_b = (const float*)d_in[12];
  const float* ln2i_g = (const float*)d_in[13];
  const float* ln2i_b = (const float*)d_in[14];
  const float* wt1    = (const float*)d_in[15];
  const float* bt1    = (const float*)d_in[16];
  const float* wt2    = (const float*)d_in[17];
  const float* bt2    = (const float*)d_in[18];
  const float* wi1    = (const float*)d_in[19];
  const float* bi1    = (const float*)d_in[20];
  const float* wi2    = (const float*)d_in[21];
  const float* bi2    = (const float*)d_in[22];
  float* out = (float*)d_out;

  char* ws = (char*)d_ws;
  bf16_t* wqkvb  = (bf16_t*)(ws + 0);
  bf16_t* wprojb = (bf16_t*)(ws + 3538944);
  bf16_t* wt1b   = (bf16_t*)(ws + 4718592);
  bf16_t* wi1b   = (bf16_t*)(ws + 9437184);
  bf16_t* wt2b   = (bf16_t*)(ws + 14155776);
  bf16_t* wi2b   = (bf16_t*)(ws + 18874368);
  bf16_t* n1     = (bf16_t*)(ws + 23592960);    // 9984x768 bf16; also n2p, o_mat
  bf16_t* x1b    = (bf16_t*)(ws + 38928384);    // 15.1MB bf16 x1; head doubles as vtmp
  bf16_t* qbuf   = (bf16_t*)(ws + 69206016);
  bf16_t* kbuf   = (bf16_t*)(ws + 84934656);
  bf16_t* vTbuf  = (bf16_t*)(ws + 100663296);
  bf16_t* biasb  = (bf16_t*)(ws + 116391936);   // 9.1 MB
  bf16_t* vtmp   = (bf16_t*)(ws + 38928384);    // dead before x1b written
  bf16_t* o_mat  = n1;
  bf16_t* n2p    = n1;
  bf16_t* hbuf   = qbuf;

  // one fused cast launch (weights + shifted bias)
  {
    CastArgs a;
    a.src[0] = w_qkv;  a.dst[0] = wqkvb;  a.n4[0] = (3 * C_ * C_) / 4;
    a.src[1] = w_proj; a.dst[1] = wprojb; a.n4[1] = (C_ * C_) / 4;
    a.src[2] = wt1;    a.dst[2] = wt1b;   a.n4[2] = (HID * C_) / 4;
    a.src[3] = wi1;    a.dst[3] = wi1b;   a.n4[3] = (HID * C_) / 4;
    a.src[4] = wt2;    a.dst[4] = wt2b;   a.n4[4] = (C_ * HID) / 4;
    a.src[5] = wi2;    a.dst[5] = wi2b;   a.n4[5] = (C_ * HID) / 4;
    a.src[6] = rel;    a.dst[6] = biasb;  a.n4[6] = (H_ * N_ * N_) / 4;
    int total4 = a.n4[0] + a.n4[1] + a.n4[2] + a.n4[3] + a.n4[4] + a.n4[5] + a.n4[6];
    cast_all<<<2048, 256, 0, stream>>>(a, total4);
  }
  ln_rows<<<M_REAL, 256, 0, stream>>>(x, ln1_g, ln1_b, n1);

  // QKV GEMM: gemm128, 77 x 18 blocks
  {
    EpiP P{}; P.bias = q_bias; P.bias2 = v_bias;
    P.ob0 = qbuf; P.ob1 = kbuf; P.ob2 = vtmp;
    gemm128<0><<<77 * 18, 256, 0, stream>>>(n1, wqkvb, wqkvb, C_, 77, 18, 0, P);
  }
  transpose_v<<<dim3(NP / 64, B_ * H_), 256, 0, stream>>>(vtmp, vTbuf);
  attn_fwd<<<1920, 256, 0, stream>>>(qbuf, kbuf, vTbuf, biasb, o_mat);

  // proj + residual -> x1 (bf16): gemm64, 154 x 6 blocks
  {
    EpiP P{}; P.bias = b_proj; P.bias_i = b_proj; P.gamma = gamma1; P.xres = x; P.outfb = x1b;
    gemm64<1><<<154 * 6, 256, 0, stream>>>(o_mat, wprojb, wprojb, C_, 154, 6, 0, P);
  }
  ln2_pack<<<M_PAD, 256, 0, stream>>>(x1b, ln2t_g, ln2t_b, ln2i_g, ln2i_b, n2p);

  // MLP fc1 + gelu: gemm128, 78 x 24 blocks (text m-blocks 0-5 -> tb=6)
  {
    EpiP P{}; P.bias = bt1; P.bias_i = bi1; P.ob0 = hbuf;
    gemm128<2><<<78 * 24, 256, 0, stream>>>(n2p, wt1b, wi1b, C_, 78, 24, 6, P);
  }
  // MLP fc2 + gamma2 residual -> d_out: gemm64, 156 x 6 blocks (tb=12)
  {
    EpiP P{}; P.bias = bt2; P.bias_i = bi2; P.gamma = gamma2; P.xresb = x1b; P.outf = out;
    gemm64<3><<<156 * 6, 256, 0, stream>>>(hbuf, wt2b, wi2b, HID, 156, 6, 12, P);
  }
}